// Round 1
// baseline (1673.562 us; speedup 1.0000x reference)
//
#include <hip/hip_runtime.h>
#include <math.h>

#define S 256
#define N 512
#define CM 256
#define CZ 128
#define H 8
#define C 32
#define HC 256
#define JC 16

// ---------------------------------------------------------------------------
// Kernel 1: per-row LayerNorm(msa) fused with v = m@Wv+bv and g = sigmoid(m@Wg+bg)
// 8 rows per block, 256 threads. Normalized rows stored transposed in LDS.
// ---------------------------------------------------------------------------
__global__ __launch_bounds__(256) void k_ln_vg(
    const float* __restrict__ msa, const float* __restrict__ gamma, const float* __restrict__ beta,
    const float* __restrict__ Wv, const float* __restrict__ bv,
    const float* __restrict__ Wg, const float* __restrict__ bg,
    float* __restrict__ vout, float* __restrict__ gout)
{
  __shared__ float xnT[CM * 8];  // [k][r]
  const int t = threadIdx.x;
  const int wav = t >> 6, lane = t & 63;
  const size_t row0 = (size_t)blockIdx.x * 8;

#pragma unroll
  for (int rr = 0; rr < 2; ++rr) {
    const int r = wav * 2 + rr;
    const float* x = msa + (row0 + r) * CM;
    const int k0 = lane * 4;
    const float4 xv = *(const float4*)(x + k0);
    float s  = xv.x + xv.y + xv.z + xv.w;
    float s2 = xv.x * xv.x + xv.y * xv.y + xv.z * xv.z + xv.w * xv.w;
#pragma unroll
    for (int off = 32; off > 0; off >>= 1) {
      s  += __shfl_xor(s, off);
      s2 += __shfl_xor(s2, off);
    }
    const float mu = s * (1.f / CM);
    const float rstd = rsqrtf(s2 * (1.f / CM) - mu * mu + 1e-5f);
    const float4 gm = *(const float4*)(gamma + k0);
    const float4 bt = *(const float4*)(beta + k0);
    xnT[(k0 + 0) * 8 + r] = (xv.x - mu) * rstd * gm.x + bt.x;
    xnT[(k0 + 1) * 8 + r] = (xv.y - mu) * rstd * gm.y + bt.y;
    xnT[(k0 + 2) * 8 + r] = (xv.z - mu) * rstd * gm.z + bt.z;
    xnT[(k0 + 3) * 8 + r] = (xv.w - mu) * rstd * gm.w + bt.w;
  }
  __syncthreads();

  float accv[8], accg[8];
  const float bvt = bv[t], bgt = bg[t];
#pragma unroll
  for (int r = 0; r < 8; ++r) { accv[r] = bvt; accg[r] = bgt; }

#pragma unroll 4
  for (int k = 0; k < CM; ++k) {
    const float wv = Wv[k * HC + t];
    const float wg = Wg[k * HC + t];
    const float4 a0 = *(const float4*)&xnT[k * 8];
    const float4 a1 = *(const float4*)&xnT[k * 8 + 4];
    accv[0] += a0.x * wv;  accg[0] += a0.x * wg;
    accv[1] += a0.y * wv;  accg[1] += a0.y * wg;
    accv[2] += a0.z * wv;  accg[2] += a0.z * wg;
    accv[3] += a0.w * wv;  accg[3] += a0.w * wg;
    accv[4] += a1.x * wv;  accg[4] += a1.x * wg;
    accv[5] += a1.y * wv;  accg[5] += a1.y * wg;
    accv[6] += a1.z * wv;  accg[6] += a1.z * wg;
    accv[7] += a1.w * wv;  accg[7] += a1.w * wg;
  }

#pragma unroll
  for (int r = 0; r < 8; ++r) {
    const size_t o = (row0 + r) * HC + t;
    vout[o] = accv[r];
    gout[o] = 1.f / (1.f + __expf(-accg[r]));
  }
}

// ---------------------------------------------------------------------------
// Kernel 2: LayerNorm(pair) @ Wb + bb  -> logits stored [i][h][j]
// one wave per (i,j) row; 4 rows per block.
// ---------------------------------------------------------------------------
__global__ __launch_bounds__(256) void k_ln_b(
    const float* __restrict__ pair, const float* __restrict__ gamma, const float* __restrict__ beta,
    const float* __restrict__ Wb, const float* __restrict__ bb, float* __restrict__ wbuf)
{
  const int t = threadIdx.x, wav = t >> 6, lane = t & 63;
  const size_t row = (size_t)blockIdx.x * 4 + wav;  // row = i*512 + j
  const float* x = pair + row * CZ;
  const int k0 = lane * 2;
  const float2 xv = *(const float2*)(x + k0);
  float s = xv.x + xv.y, s2 = xv.x * xv.x + xv.y * xv.y;
#pragma unroll
  for (int off = 32; off > 0; off >>= 1) {
    s  += __shfl_xor(s, off);
    s2 += __shfl_xor(s2, off);
  }
  const float mu = s * (1.f / CZ);
  const float rstd = rsqrtf(s2 * (1.f / CZ) - mu * mu + 1e-5f);
  const float2 gm = *(const float2*)(gamma + k0);
  const float2 bt = *(const float2*)(beta + k0);
  const float x0 = (xv.x - mu) * rstd * gm.x + bt.x;
  const float x1 = (xv.y - mu) * rstd * gm.y + bt.y;

  // Wb rows k0 and k0+1 (8 floats each), 16 consecutive floats
  const float4* wb4 = (const float4*)(Wb + k0 * H);
  const float4 w0 = wb4[0], w1 = wb4[1], w2 = wb4[2], w3 = wb4[3];
  float acc[8];
  acc[0] = x0 * w0.x + x1 * w2.x;
  acc[1] = x0 * w0.y + x1 * w2.y;
  acc[2] = x0 * w0.z + x1 * w2.z;
  acc[3] = x0 * w0.w + x1 * w2.w;
  acc[4] = x0 * w1.x + x1 * w3.x;
  acc[5] = x0 * w1.y + x1 * w3.y;
  acc[6] = x0 * w1.z + x1 * w3.z;
  acc[7] = x0 * w1.w + x1 * w3.w;
#pragma unroll
  for (int h = 0; h < 8; ++h) {
#pragma unroll
    for (int off = 32; off > 0; off >>= 1) acc[h] += __shfl_xor(acc[h], off);
  }
  if (lane == 0) {
    const size_t i = row >> 9;
    const size_t j = row & 511;
#pragma unroll
    for (int h = 0; h < 8; ++h)
      wbuf[(i * H + h) * N + j] = acc[h] + bb[h];
  }
}

// ---------------------------------------------------------------------------
// Kernel 3: softmax over j (contiguous 512) per (i,h) row, in place
// ---------------------------------------------------------------------------
__global__ __launch_bounds__(256) void k_softmax(float* __restrict__ wbuf)
{
  float* p = wbuf + (size_t)blockIdx.x * N;
  const int t = threadIdx.x, lane = t & 63, wav = t >> 6;
  float2 xv = *(float2*)(p + t * 2);
  float mx = fmaxf(xv.x, xv.y);
#pragma unroll
  for (int off = 32; off > 0; off >>= 1) mx = fmaxf(mx, __shfl_xor(mx, off));
  __shared__ float redmax[4];
  __shared__ float redsum[4];
  if (lane == 0) redmax[wav] = mx;
  __syncthreads();
  mx = fmaxf(fmaxf(redmax[0], redmax[1]), fmaxf(redmax[2], redmax[3]));
  const float e0 = __expf(xv.x - mx), e1 = __expf(xv.y - mx);
  float sum = e0 + e1;
#pragma unroll
  for (int off = 32; off > 0; off >>= 1) sum += __shfl_xor(sum, off);
  if (lane == 0) redsum[wav] = sum;
  __syncthreads();
  sum = (redsum[0] + redsum[1]) + (redsum[2] + redsum[3]);
  const float inv = 1.f / sum;
  *(float2*)(p + t * 2) = make_float2(e0 * inv, e1 * inv);
}

// ---------------------------------------------------------------------------
// Kernel 4: o[s,i,h,c] = sum_j w[i,j,h] * v[s,j,h,c], gated by g, written over g.
// Block: fixed h, 32 i x 8 s tile; thread owns one (i,s), all 32 c.
// ---------------------------------------------------------------------------
__global__ __launch_bounds__(256) void k_attn(
    const float* __restrict__ vbuf, const float* __restrict__ wbuf, float* __restrict__ gbuf)
{
  __shared__ float wt[32][JC + 1];
  __shared__ float vt[JC][8][C];
  const int t = threadIdx.x;
  const int il = t & 31, sl = t >> 5;
  const int i0 = blockIdx.x * 32, s0 = blockIdx.y * 8, h = blockIdx.z;

  float4 acc[8];
#pragma unroll
  for (int q = 0; q < 8; ++q) acc[q] = make_float4(0.f, 0.f, 0.f, 0.f);

  for (int jc = 0; jc < N; jc += JC) {
    __syncthreads();
    // stage w tile: 32 x 16
    {
      const int wil = t >> 3, wjj = (t & 7) * 2;
      *(float2*)&wt[wil][wjj] =
          *(const float2*)&wbuf[((size_t)(i0 + wil) * H + h) * N + jc + wjj];
    }
    // stage v tile: 8 s x 16 j x 32 c = 1024 float4 slots, 4 per thread
#pragma unroll
    for (int q = 0; q < 4; ++q) {
      const int slot = t + 256 * q;
      const int c4 = slot & 7, jj = (slot >> 3) & 15, ssl = slot >> 7;
      const float4 vv = *(const float4*)&vbuf[((size_t)(s0 + ssl) * N + jc + jj) * HC + h * C + c4 * 4];
      *(float4*)&vt[jj][ssl][c4 * 4] = vv;
    }
    __syncthreads();
#pragma unroll
    for (int jj = 0; jj < JC; ++jj) {
      const float wij = wt[il][jj];
#pragma unroll
      for (int q = 0; q < 8; ++q) {
        const float4 vv = *(const float4*)&vt[jj][sl][q * 4];
        acc[q].x += wij * vv.x;
        acc[q].y += wij * vv.y;
        acc[q].z += wij * vv.z;
        acc[q].w += wij * vv.w;
      }
    }
  }

  float* gp = gbuf + ((size_t)(s0 + sl) * N + i0 + il) * HC + h * C;
#pragma unroll
  for (int q = 0; q < 8; ++q) {
    float4 gv = *(float4*)(gp + q * 4);
    gv.x *= acc[q].x; gv.y *= acc[q].y; gv.z *= acc[q].z; gv.w *= acc[q].w;
    *(float4*)(gp + q * 4) = gv;
  }
}

// ---------------------------------------------------------------------------
// Kernel 5: out = o_gated @ Wp   [131072 x 256] x [256 x 256]
// ---------------------------------------------------------------------------
__global__ __launch_bounds__(256) void k_out(
    const float* __restrict__ og, const float* __restrict__ Wp, float* __restrict__ out)
{
  __shared__ float xT[HC * 8];
  const int t = threadIdx.x;
  const size_t row0 = (size_t)blockIdx.x * 8;
  {
    const int r = t >> 5, k0 = (t & 31) * 8;
    const float4 a0 = *(const float4*)&og[(row0 + r) * HC + k0];
    const float4 a1 = *(const float4*)&og[(row0 + r) * HC + k0 + 4];
    xT[(k0 + 0) * 8 + r] = a0.x;
    xT[(k0 + 1) * 8 + r] = a0.y;
    xT[(k0 + 2) * 8 + r] = a0.z;
    xT[(k0 + 3) * 8 + r] = a0.w;
    xT[(k0 + 4) * 8 + r] = a1.x;
    xT[(k0 + 5) * 8 + r] = a1.y;
    xT[(k0 + 6) * 8 + r] = a1.z;
    xT[(k0 + 7) * 8 + r] = a1.w;
  }
  __syncthreads();

  float acc[8];
#pragma unroll
  for (int r = 0; r < 8; ++r) acc[r] = 0.f;
#pragma unroll 4
  for (int k = 0; k < HC; ++k) {
    const float wp = Wp[k * CM + t];
    const float4 a0 = *(const float4*)&xT[k * 8];
    const float4 a1 = *(const float4*)&xT[k * 8 + 4];
    acc[0] += a0.x * wp;
    acc[1] += a0.y * wp;
    acc[2] += a0.z * wp;
    acc[3] += a0.w * wp;
    acc[4] += a1.x * wp;
    acc[5] += a1.y * wp;
    acc[6] += a1.z * wp;
    acc[7] += a1.w * wp;
  }
#pragma unroll
  for (int r = 0; r < 8; ++r) out[(row0 + r) * CM + t] = acc[r];
}

// ---------------------------------------------------------------------------
extern "C" void kernel_launch(void* const* d_in, const int* in_sizes, int n_in,
                              void* d_out, int out_size, void* d_ws, size_t ws_size,
                              hipStream_t stream)
{
  const float* msa      = (const float*)d_in[0];
  const float* pair     = (const float*)d_in[1];
  const float* ln_msa_g = (const float*)d_in[2];
  const float* ln_msa_b = (const float*)d_in[3];
  const float* Wv       = (const float*)d_in[4];
  const float* bv       = (const float*)d_in[5];
  const float* ln_z_g   = (const float*)d_in[6];
  const float* ln_z_b   = (const float*)d_in[7];
  const float* Wb       = (const float*)d_in[8];
  const float* bb       = (const float*)d_in[9];
  const float* Wg       = (const float*)d_in[10];
  const float* bg       = (const float*)d_in[11];
  const float* Wp       = (const float*)d_in[12];
  float* out = (float*)d_out;

  float* vbuf = (float*)d_ws;                    // [S,N,H,C]   134.2 MB
  float* gbuf = vbuf + (size_t)S * N * HC;       // [S,N,H,C]   134.2 MB (becomes o_gated)
  float* wbuf = gbuf + (size_t)S * N * HC;       // [N,H,N]       8.4 MB

  k_ln_vg<<<S * N / 8, 256, 0, stream>>>(msa, ln_msa_g, ln_msa_b, Wv, bv, Wg, bg, vbuf, gbuf);
  k_ln_b<<<N * N / 4, 256, 0, stream>>>(pair, ln_z_g, ln_z_b, Wb, bb, wbuf);
  k_softmax<<<N * H, 256, 0, stream>>>(wbuf);
  dim3 g4(N / 32, S / 8, H);
  k_attn<<<g4, 256, 0, stream>>>(vbuf, wbuf, gbuf);
  k_out<<<S * N / 8, 256, 0, stream>>>(gbuf, Wp, out);
}

// Round 2
// 1084.176 us; speedup vs baseline: 1.5436x; 1.5436x over previous
//
#include <hip/hip_runtime.h>
#include <hip/hip_bf16.h>
#include <math.h>

#define S 256
#define N 512
#define CM 256
#define CZ 128
#define H 8
#define C 32
#define HC 256
#define JC 16

typedef __attribute__((ext_vector_type(8))) short short8v;
typedef __attribute__((ext_vector_type(4))) float f32x4;

#define GLOBAL_LOAD_LDS16(gsrc, ldst)                                          \
  __builtin_amdgcn_global_load_lds(                                            \
      (const __attribute__((address_space(1))) void*)(gsrc),                   \
      (__attribute__((address_space(3))) void*)(ldst), 16, 0, 0)

// ---------------------------------------------------------------------------
// Kernel 1: per-row LayerNorm(msa) fused with v = m@Wv+bv and g = sigmoid(m@Wg+bg)
// 8 rows per block, 256 threads. v written bf16 in chunked layout
// [h][j/8][s*32+c][j%8] (8 consecutive j packed per 16B chunk, coalesced).
// ---------------------------------------------------------------------------
__global__ __launch_bounds__(256) void k_ln_vg(
    const float* __restrict__ msa, const float* __restrict__ gamma, const float* __restrict__ beta,
    const float* __restrict__ Wv, const float* __restrict__ bv,
    const float* __restrict__ Wg, const float* __restrict__ bg,
    __hip_bfloat16* __restrict__ vc, float* __restrict__ gout)
{
  __shared__ float xnT[CM * 8];  // [k][r]
  const int t = threadIdx.x;
  const int wav = t >> 6, lane = t & 63;
  const size_t row0 = (size_t)blockIdx.x * 8;

#pragma unroll
  for (int rr = 0; rr < 2; ++rr) {
    const int r = wav * 2 + rr;
    const float* x = msa + (row0 + r) * CM;
    const int k0 = lane * 4;
    const float4 xv = *(const float4*)(x + k0);
    float s  = xv.x + xv.y + xv.z + xv.w;
    float s2 = xv.x * xv.x + xv.y * xv.y + xv.z * xv.z + xv.w * xv.w;
#pragma unroll
    for (int off = 32; off > 0; off >>= 1) {
      s  += __shfl_xor(s, off);
      s2 += __shfl_xor(s2, off);
    }
    const float mu = s * (1.f / CM);
    const float rstd = rsqrtf(s2 * (1.f / CM) - mu * mu + 1e-5f);
    const float4 gm = *(const float4*)(gamma + k0);
    const float4 bt = *(const float4*)(beta + k0);
    xnT[(k0 + 0) * 8 + r] = (xv.x - mu) * rstd * gm.x + bt.x;
    xnT[(k0 + 1) * 8 + r] = (xv.y - mu) * rstd * gm.y + bt.y;
    xnT[(k0 + 2) * 8 + r] = (xv.z - mu) * rstd * gm.z + bt.z;
    xnT[(k0 + 3) * 8 + r] = (xv.w - mu) * rstd * gm.w + bt.w;
  }
  __syncthreads();

  float accv[8], accg[8];
  const float bvt = bv[t], bgt = bg[t];
#pragma unroll
  for (int r = 0; r < 8; ++r) { accv[r] = bvt; accg[r] = bgt; }

#pragma unroll 4
  for (int k = 0; k < CM; ++k) {
    const float wv = Wv[k * HC + t];
    const float wg = Wg[k * HC + t];
    const float4 a0 = *(const float4*)&xnT[k * 8];
    const float4 a1 = *(const float4*)&xnT[k * 8 + 4];
    accv[0] += a0.x * wv;  accg[0] += a0.x * wg;
    accv[1] += a0.y * wv;  accg[1] += a0.y * wg;
    accv[2] += a0.z * wv;  accg[2] += a0.z * wg;
    accv[3] += a0.w * wv;  accg[3] += a0.w * wg;
    accv[4] += a1.x * wv;  accg[4] += a1.x * wg;
    accv[5] += a1.y * wv;  accg[5] += a1.y * wg;
    accv[6] += a1.z * wv;  accg[6] += a1.z * wg;
    accv[7] += a1.w * wv;  accg[7] += a1.w * wg;
  }

  // v store: this block's 8 rows are 8 consecutive j at fixed s (row0 % 8 == 0,
  // 512 % 8 == 0), exactly one chunk of the [h][j/8][n][j%8] layout per thread.
  {
    const int hh = t >> 5, cc = t & 31;
    const int sidx = (int)(row0 >> 9);
    const int jb = ((int)(row0 & (N - 1))) >> 3;
    union { __hip_bfloat16 b[8]; short8v v; } pk;
#pragma unroll
    for (int r = 0; r < 8; ++r) pk.b[r] = __float2bfloat16(accv[r]);
    *(short8v*)(vc + ((((size_t)hh * (N / 8) + jb) * (S * C)) + sidx * C + cc) * 8) = pk.v;
  }
#pragma unroll
  for (int r = 0; r < 8; ++r)
    gout[(row0 + r) * HC + t] = 1.f / (1.f + __expf(-accg[r]));
}

// ---------------------------------------------------------------------------
// Kernel 2: LayerNorm(pair) @ Wb + bb  -> logits stored [h][i][j] fp32
// ---------------------------------------------------------------------------
__global__ __launch_bounds__(256) void k_ln_b(
    const float* __restrict__ pair, const float* __restrict__ gamma, const float* __restrict__ beta,
    const float* __restrict__ Wb, const float* __restrict__ bb, float* __restrict__ wbuf)
{
  const int t = threadIdx.x, wav = t >> 6, lane = t & 63;
  const size_t row = (size_t)blockIdx.x * 4 + wav;  // row = i*512 + j
  const float* x = pair + row * CZ;
  const int k0 = lane * 2;
  const float2 xv = *(const float2*)(x + k0);
  float s = xv.x + xv.y, s2 = xv.x * xv.x + xv.y * xv.y;
#pragma unroll
  for (int off = 32; off > 0; off >>= 1) {
    s  += __shfl_xor(s, off);
    s2 += __shfl_xor(s2, off);
  }
  const float mu = s * (1.f / CZ);
  const float rstd = rsqrtf(s2 * (1.f / CZ) - mu * mu + 1e-5f);
  const float2 gm = *(const float2*)(gamma + k0);
  const float2 bt = *(const float2*)(beta + k0);
  const float x0 = (xv.x - mu) * rstd * gm.x + bt.x;
  const float x1 = (xv.y - mu) * rstd * gm.y + bt.y;

  const float4* wb4 = (const float4*)(Wb + k0 * H);
  const float4 w0 = wb4[0], w1 = wb4[1], w2 = wb4[2], w3 = wb4[3];
  float acc[8];
  acc[0] = x0 * w0.x + x1 * w2.x;
  acc[1] = x0 * w0.y + x1 * w2.y;
  acc[2] = x0 * w0.z + x1 * w2.z;
  acc[3] = x0 * w0.w + x1 * w2.w;
  acc[4] = x0 * w1.x + x1 * w3.x;
  acc[5] = x0 * w1.y + x1 * w3.y;
  acc[6] = x0 * w1.z + x1 * w3.z;
  acc[7] = x0 * w1.w + x1 * w3.w;
#pragma unroll
  for (int h = 0; h < 8; ++h) {
#pragma unroll
    for (int off = 32; off > 0; off >>= 1) acc[h] += __shfl_xor(acc[h], off);
  }
  if (lane == 0) {
    const size_t i = row >> 9;
    const size_t j = row & (N - 1);
#pragma unroll
    for (int h = 0; h < 8; ++h)
      wbuf[((size_t)h * N + i) * N + j] = acc[h] + bb[h];
  }
}

// ---------------------------------------------------------------------------
// Kernel 3: softmax over j per (h,i) row; fp32 logits in, bf16 weights out.
// ---------------------------------------------------------------------------
__global__ __launch_bounds__(256) void k_softmax(
    const float* __restrict__ wbuf, __hip_bfloat16* __restrict__ wbh)
{
  const float* p = wbuf + (size_t)blockIdx.x * N;
  const int t = threadIdx.x, lane = t & 63, wav = t >> 6;
  float2 xv = *(const float2*)(p + t * 2);
  float mx = fmaxf(xv.x, xv.y);
#pragma unroll
  for (int off = 32; off > 0; off >>= 1) mx = fmaxf(mx, __shfl_xor(mx, off));
  __shared__ float redmax[4];
  __shared__ float redsum[4];
  if (lane == 0) redmax[wav] = mx;
  __syncthreads();
  mx = fmaxf(fmaxf(redmax[0], redmax[1]), fmaxf(redmax[2], redmax[3]));
  const float e0 = __expf(xv.x - mx), e1 = __expf(xv.y - mx);
  float sum = e0 + e1;
#pragma unroll
  for (int off = 32; off > 0; off >>= 1) sum += __shfl_xor(sum, off);
  if (lane == 0) redsum[wav] = sum;
  __syncthreads();
  sum = (redsum[0] + redsum[1]) + (redsum[2] + redsum[3]);
  const float inv = 1.f / sum;
  union { __hip_bfloat16 b[2]; int i; } pk;
  pk.b[0] = __float2bfloat16(e0 * inv);
  pk.b[1] = __float2bfloat16(e1 * inv);
  *(int*)((__hip_bfloat16*)(wbh + (size_t)blockIdx.x * N) + t * 2) = pk.i;
}

// ---------------------------------------------------------------------------
// Kernel 4 (MFMA): per h, O[i][(s,c)] = W_h[i][j] x V_h[j][(s,c)],
// M=512, K=512, Nout=8192.  BM=BN=128, BK=64.  4 waves, each 64x64.
// A = wbh [h][i][j] bf16 (16B = 8 consecutive j).
// B = vc  [h][j/8][n][j%8] bf16 (16B = 8 consecutive j at fixed n).
// Both staged via global_load_lds into chunked LDS [jb][rowidx][8]:
// fragment ds_read_b128 is 16-lane x 16B contiguous -> conflict-free.
// Epilogue multiplies by gate g and writes og fp32 in place over g.
// ---------------------------------------------------------------------------
__global__ __launch_bounds__(256) void k_attn_mfma(
    const __hip_bfloat16* __restrict__ vc, const __hip_bfloat16* __restrict__ wbh,
    float* __restrict__ gbuf)
{
  __shared__ __hip_bfloat16 Ac[8 * 128 * 8];  // [jb][i_local][jr]
  __shared__ __hip_bfloat16 Bc[8 * 128 * 8];  // [jb][n_local][jr]

  const int t = threadIdx.x;
  const int wave = t >> 6, lane = t & 63;
  const int wm = wave >> 1, wn = wave & 1;
  const int lr = lane & 15, lq = lane >> 4;
  const int n0 = blockIdx.x * 128;
  const int i0 = blockIdx.y * 128;
  const int h  = blockIdx.z;

  f32x4 acc[4][4];
#pragma unroll
  for (int mi = 0; mi < 4; ++mi)
#pragma unroll
    for (int ni = 0; ni < 4; ++ni) acc[mi][ni] = (f32x4)0.f;

  const __hip_bfloat16* Abase = wbh + ((size_t)h * N + i0) * N;
  const __hip_bfloat16* Bbase = vc + (size_t)h * (N / 8) * (S * C) * 8 + (size_t)n0 * 8;

  for (int kt = 0; kt < N / 64; ++kt) {
    __syncthreads();  // previous compute done before restaging
    // stage: each wave issues 4 A-chunks + 4 B-chunks of 1KB (64 lanes x 16B)
#pragma unroll
    for (int u = 0; u < 2; ++u) {
      const int jb = wave * 2 + u;
#pragma unroll
      for (int ih = 0; ih < 2; ++ih) {
        const __hip_bfloat16* asrc = Abase + ((size_t)(ih * 64 + lane)) * N + kt * 64 + jb * 8;
        GLOBAL_LOAD_LDS16(asrc, &Ac[(jb * 128 + ih * 64) * 8]);
        const __hip_bfloat16* bsrc = Bbase + ((size_t)(kt * 8 + jb) * (S * C) + ih * 64 + lane) * 8;
        GLOBAL_LOAD_LDS16(bsrc, &Bc[(jb * 128 + ih * 64) * 8]);
      }
    }
    __syncthreads();  // compiler drains vmcnt before barrier

#pragma unroll
    for (int kh = 0; kh < 2; ++kh) {
      const int ldb = lq + kh * 4;
      short8v a[4], b[4];
#pragma unroll
      for (int mi = 0; mi < 4; ++mi)
        a[mi] = *(const short8v*)&Ac[((ldb * 128) + wm * 64 + mi * 16 + lr) * 8];
#pragma unroll
      for (int ni = 0; ni < 4; ++ni)
        b[ni] = *(const short8v*)&Bc[((ldb * 128) + wn * 64 + ni * 16 + lr) * 8];
#pragma unroll
      for (int mi = 0; mi < 4; ++mi)
#pragma unroll
        for (int ni = 0; ni < 4; ++ni)
          acc[mi][ni] = __builtin_amdgcn_mfma_f32_16x16x32_bf16(a[mi], b[ni], acc[mi][ni], 0, 0, 0);
    }
  }

  // epilogue: gate and write og over gbuf (one thread owns each element)
#pragma unroll
  for (int mi = 0; mi < 4; ++mi)
#pragma unroll
    for (int ni = 0; ni < 4; ++ni) {
      const int n = n0 + wn * 64 + ni * 16 + lr;
      const int sidx = n >> 5, c = n & 31;
#pragma unroll
      for (int r = 0; r < 4; ++r) {
        const int i = i0 + wm * 64 + mi * 16 + lq * 4 + r;
        const size_t idx = (((size_t)sidx * N + i) << 8) + h * C + c;
        gbuf[idx] = gbuf[idx] * acc[mi][ni][r];
      }
    }
}

// ---------------------------------------------------------------------------
// Kernel 5: out = o_gated @ Wp   [131072 x 256] x [256 x 256]   (fp32)
// ---------------------------------------------------------------------------
__global__ __launch_bounds__(256) void k_out(
    const float* __restrict__ og, const float* __restrict__ Wp, float* __restrict__ out)
{
  __shared__ float xT[HC * 8];
  const int t = threadIdx.x;
  const size_t row0 = (size_t)blockIdx.x * 8;
  {
    const int r = t >> 5, k0 = (t & 31) * 8;
    const float4 a0 = *(const float4*)&og[(row0 + r) * HC + k0];
    const float4 a1 = *(const float4*)&og[(row0 + r) * HC + k0 + 4];
    xT[(k0 + 0) * 8 + r] = a0.x;
    xT[(k0 + 1) * 8 + r] = a0.y;
    xT[(k0 + 2) * 8 + r] = a0.z;
    xT[(k0 + 3) * 8 + r] = a0.w;
    xT[(k0 + 4) * 8 + r] = a1.x;
    xT[(k0 + 5) * 8 + r] = a1.y;
    xT[(k0 + 6) * 8 + r] = a1.z;
    xT[(k0 + 7) * 8 + r] = a1.w;
  }
  __syncthreads();

  float acc[8];
#pragma unroll
  for (int r = 0; r < 8; ++r) acc[r] = 0.f;
#pragma unroll 4
  for (int k = 0; k < HC; ++k) {
    const float wp = Wp[k * CM + t];
    const float4 a0 = *(const float4*)&xT[k * 8];
    const float4 a1 = *(const float4*)&xT[k * 8 + 4];
    acc[0] += a0.x * wp;
    acc[1] += a0.y * wp;
    acc[2] += a0.z * wp;
    acc[3] += a0.w * wp;
    acc[4] += a1.x * wp;
    acc[5] += a1.y * wp;
    acc[6] += a1.z * wp;
    acc[7] += a1.w * wp;
  }
#pragma unroll
  for (int r = 0; r < 8; ++r) out[(row0 + r) * CM + t] = acc[r];
}

// ---------------------------------------------------------------------------
extern "C" void kernel_launch(void* const* d_in, const int* in_sizes, int n_in,
                              void* d_out, int out_size, void* d_ws, size_t ws_size,
                              hipStream_t stream)
{
  const float* msa      = (const float*)d_in[0];
  const float* pair     = (const float*)d_in[1];
  const float* ln_msa_g = (const float*)d_in[2];
  const float* ln_msa_b = (const float*)d_in[3];
  const float* Wv       = (const float*)d_in[4];
  const float* bv       = (const float*)d_in[5];
  const float* ln_z_g   = (const float*)d_in[6];
  const float* ln_z_b   = (const float*)d_in[7];
  const float* Wb       = (const float*)d_in[8];
  const float* bb       = (const float*)d_in[9];
  const float* Wg       = (const float*)d_in[10];
  const float* bg       = (const float*)d_in[11];
  const float* Wp       = (const float*)d_in[12];
  float* out = (float*)d_out;

  // ws layout
  __hip_bfloat16* vc = (__hip_bfloat16*)d_ws;                       // 67.1 MB  [h][j/8][s*32+c][j%8]
  float* gbuf = (float*)((char*)d_ws + (size_t)H * (N / 8) * (S * C) * 8 * 2);  // 134.2 MB
  float* wbuf = gbuf + (size_t)S * N * HC;                          // 8.4 MB   [h][i][j] logits
  __hip_bfloat16* wbh = (__hip_bfloat16*)(wbuf + (size_t)N * H * N); // 4.2 MB  [h][i][j] bf16

  k_ln_vg<<<S * N / 8, 256, 0, stream>>>(msa, ln_msa_g, ln_msa_b, Wv, bv, Wg, bg, vc, gbuf);
  k_ln_b<<<N * N / 4, 256, 0, stream>>>(pair, ln_z_g, ln_z_b, Wb, bb, wbuf);
  k_softmax<<<N * H, 256, 0, stream>>>(wbuf, wbh);
  dim3 g4(S * C / 128, N / 128, H);
  k_attn_mfma<<<g4, 256, 0, stream>>>(vc, wbh, gbuf);
  k_out<<<S * N / 8, 256, 0, stream>>>(gbuf, Wp, out);
}

// Round 3
// 444.851 us; speedup vs baseline: 3.7621x; 2.4372x over previous
//
#include <hip/hip_runtime.h>
#include <hip/hip_bf16.h>
#include <math.h>

#define S 256
#define N 512
#define CM 256
#define CZ 128
#define H 8
#define C 32
#define HC 256

typedef __attribute__((ext_vector_type(8))) short short8v;
typedef __attribute__((ext_vector_type(4))) float f32x4;

#define GLOBAL_LOAD_LDS16(gsrc, ldst)                                          \
  __builtin_amdgcn_global_load_lds(                                            \
      (const __attribute__((address_space(1))) void*)(gsrc),                   \
      (__attribute__((address_space(3))) void*)(ldst), 16, 0, 0)

// ---------------------------------------------------------------------------
// Kernel 0: weight prep. Wcat_t[n][k] = bf16(Wv[k][n]) (n<256) / Wg[k][n-256];
// Wp_t[n][k] = bf16(Wp[k][n]).  B^T layouts for MFMA B-fragments.
// ---------------------------------------------------------------------------
__global__ __launch_bounds__(256) void k_prep(
    const float* __restrict__ Wv, const float* __restrict__ Wg, const float* __restrict__ Wp,
    __hip_bfloat16* __restrict__ Wcat_t, __hip_bfloat16* __restrict__ Wp_t)
{
  const int k = blockIdx.x;   // 256
  const int n = threadIdx.x;  // 256
  Wcat_t[(size_t)n * CM + k]        = __float2bfloat16(Wv[(size_t)k * HC + n]);
  Wcat_t[(size_t)(n + HC) * CM + k] = __float2bfloat16(Wg[(size_t)k * HC + n]);
  Wp_t[(size_t)n * CM + k]          = __float2bfloat16(Wp[(size_t)k * CM + n]);
}

// ---------------------------------------------------------------------------
// Kernel 1: row LayerNorm of msa -> bf16 [131072][256]. One wave per row.
// ---------------------------------------------------------------------------
__global__ __launch_bounds__(256) void k_ln(
    const float* __restrict__ msa, const float* __restrict__ gamma, const float* __restrict__ beta,
    __hip_bfloat16* __restrict__ mbf)
{
  const int t = threadIdx.x, wav = t >> 6, lane = t & 63;
  const size_t row = (size_t)blockIdx.x * 4 + wav;
  const int k0 = lane * 4;
  const float4 xv = *(const float4*)(msa + row * CM + k0);
  float s  = xv.x + xv.y + xv.z + xv.w;
  float s2 = xv.x * xv.x + xv.y * xv.y + xv.z * xv.z + xv.w * xv.w;
#pragma unroll
  for (int off = 32; off > 0; off >>= 1) {
    s  += __shfl_xor(s, off);
    s2 += __shfl_xor(s2, off);
  }
  const float mu = s * (1.f / CM);
  const float rstd = rsqrtf(s2 * (1.f / CM) - mu * mu + 1e-5f);
  const float4 gm = *(const float4*)(gamma + k0);
  const float4 bt = *(const float4*)(beta + k0);
  union { __hip_bfloat16 b[4]; short4 v; } pk;
  pk.b[0] = __float2bfloat16((xv.x - mu) * rstd * gm.x + bt.x);
  pk.b[1] = __float2bfloat16((xv.y - mu) * rstd * gm.y + bt.y);
  pk.b[2] = __float2bfloat16((xv.z - mu) * rstd * gm.z + bt.z);
  pk.b[3] = __float2bfloat16((xv.w - mu) * rstd * gm.w + bt.w);
  *(short4*)(mbf + row * CM + k0) = pk.v;
}

// ---------------------------------------------------------------------------
// Kernel 2 (MFMA): D = mbf[131072x256] @ Wcat[256x512] + bias.
// cols <256: v -> chunked vc [h][j/8][s*32+c][j%8] bf16 (8B packed stores)
// cols >=256: g = sigmoid   -> gb [row][col'] bf16
// BM=BN=128, BK=64, 4 waves of 64x64. Identical frag pattern to k_attn_mfma.
// ---------------------------------------------------------------------------
__global__ __launch_bounds__(256) void k_mm1(
    const __hip_bfloat16* __restrict__ mbf, const __hip_bfloat16* __restrict__ Wcat_t,
    const float* __restrict__ bv, const float* __restrict__ bg,
    __hip_bfloat16* __restrict__ vc, __hip_bfloat16* __restrict__ gb)
{
  __shared__ __hip_bfloat16 Ac[8 * 128 * 8];  // [kb][m_local][kr]
  __shared__ __hip_bfloat16 Bc[8 * 128 * 8];  // [kb][n_local][kr]
  const int t = threadIdx.x;
  const int wave = t >> 6, lane = t & 63;
  const int wm = wave >> 1, wn = wave & 1;
  const int lr = lane & 15, lq = lane >> 4;
  const int n0 = blockIdx.x * 128;
  const int m0 = blockIdx.y * 128;

  float bias[4];
#pragma unroll
  for (int ni = 0; ni < 4; ++ni) {
    const int col = n0 + wn * 64 + ni * 16 + lr;
    bias[ni] = (col < HC) ? bv[col] : bg[col - HC];
  }
  f32x4 acc[4][4];
#pragma unroll
  for (int mi = 0; mi < 4; ++mi)
#pragma unroll
    for (int ni = 0; ni < 4; ++ni) acc[mi][ni] = (f32x4)bias[ni];

  for (int kt = 0; kt < CM / 64; ++kt) {
    __syncthreads();
#pragma unroll
    for (int u = 0; u < 2; ++u) {
      const int jb = wave * 2 + u;
#pragma unroll
      for (int ih = 0; ih < 2; ++ih) {
        const __hip_bfloat16* asrc = mbf + ((size_t)(m0 + ih * 64 + lane)) * CM + kt * 64 + jb * 8;
        GLOBAL_LOAD_LDS16(asrc, &Ac[(jb * 128 + ih * 64) * 8]);
        const __hip_bfloat16* bsrc = Wcat_t + ((size_t)(n0 + ih * 64 + lane)) * CM + kt * 64 + jb * 8;
        GLOBAL_LOAD_LDS16(bsrc, &Bc[(jb * 128 + ih * 64) * 8]);
      }
    }
    __syncthreads();
#pragma unroll
    for (int kh = 0; kh < 2; ++kh) {
      const int ldb = lq + kh * 4;
      short8v a[4], b[4];
#pragma unroll
      for (int mi = 0; mi < 4; ++mi)
        a[mi] = *(const short8v*)&Ac[((ldb * 128) + wm * 64 + mi * 16 + lr) * 8];
#pragma unroll
      for (int ni = 0; ni < 4; ++ni)
        b[ni] = *(const short8v*)&Bc[((ldb * 128) + wn * 64 + ni * 16 + lr) * 8];
#pragma unroll
      for (int mi = 0; mi < 4; ++mi)
#pragma unroll
        for (int ni = 0; ni < 4; ++ni)
          acc[mi][ni] = __builtin_amdgcn_mfma_f32_16x16x32_bf16(a[mi], b[ni], acc[mi][ni], 0, 0, 0);
    }
  }

  if (n0 < HC) {  // v half -> chunked layout, 4 consecutive j per lane = 8B store
#pragma unroll
    for (int mi = 0; mi < 4; ++mi) {
      const int rowb = m0 + wm * 64 + mi * 16 + lq * 4;
      const int s = rowb >> 9;
      const int j = rowb & (N - 1);
      const int jb = j >> 3, jlo = (lq & 1) * 4;
#pragma unroll
      for (int ni = 0; ni < 4; ++ni) {
        const int col = n0 + wn * 64 + ni * 16 + lr;
        const int h = col >> 5, c = col & 31;
        union { __hip_bfloat16 b[4]; short4 v; } pk;
#pragma unroll
        for (int r = 0; r < 4; ++r) pk.b[r] = __float2bfloat16(acc[mi][ni][r]);
        *(short4*)(vc + ((size_t)(h * (N / 8) + jb) * (S * C) + s * C + c) * 8 + jlo) = pk.v;
      }
    }
  } else {  // g half
#pragma unroll
    for (int mi = 0; mi < 4; ++mi) {
      const int rowb = m0 + wm * 64 + mi * 16 + lq * 4;
#pragma unroll
      for (int ni = 0; ni < 4; ++ni) {
        const int colp = (n0 - HC) + wn * 64 + ni * 16 + lr;
#pragma unroll
        for (int r = 0; r < 4; ++r)
          gb[(size_t)(rowb + r) * HC + colp] =
              __float2bfloat16(1.f / (1.f + __expf(-acc[mi][ni][r])));
      }
    }
  }
}

// ---------------------------------------------------------------------------
// Kernel 3: LayerNorm(pair) @ Wb + bb  -> logits stored [h][i][j] fp32
// ---------------------------------------------------------------------------
__global__ __launch_bounds__(256) void k_ln_b(
    const float* __restrict__ pair, const float* __restrict__ gamma, const float* __restrict__ beta,
    const float* __restrict__ Wb, const float* __restrict__ bb, float* __restrict__ wbuf)
{
  const int t = threadIdx.x, wav = t >> 6, lane = t & 63;
  const size_t row = (size_t)blockIdx.x * 4 + wav;  // row = i*512 + j
  const float* x = pair + row * CZ;
  const int k0 = lane * 2;
  const float2 xv = *(const float2*)(x + k0);
  float s = xv.x + xv.y, s2 = xv.x * xv.x + xv.y * xv.y;
#pragma unroll
  for (int off = 32; off > 0; off >>= 1) {
    s  += __shfl_xor(s, off);
    s2 += __shfl_xor(s2, off);
  }
  const float mu = s * (1.f / CZ);
  const float rstd = rsqrtf(s2 * (1.f / CZ) - mu * mu + 1e-5f);
  const float2 gm = *(const float2*)(gamma + k0);
  const float2 bt = *(const float2*)(beta + k0);
  const float x0 = (xv.x - mu) * rstd * gm.x + bt.x;
  const float x1 = (xv.y - mu) * rstd * gm.y + bt.y;

  const float4* wb4 = (const float4*)(Wb + k0 * H);
  const float4 w0 = wb4[0], w1 = wb4[1], w2 = wb4[2], w3 = wb4[3];
  float acc[8];
  acc[0] = x0 * w0.x + x1 * w2.x;
  acc[1] = x0 * w0.y + x1 * w2.y;
  acc[2] = x0 * w0.z + x1 * w2.z;
  acc[3] = x0 * w0.w + x1 * w2.w;
  acc[4] = x0 * w1.x + x1 * w3.x;
  acc[5] = x0 * w1.y + x1 * w3.y;
  acc[6] = x0 * w1.z + x1 * w3.z;
  acc[7] = x0 * w1.w + x1 * w3.w;
#pragma unroll
  for (int h = 0; h < 8; ++h) {
#pragma unroll
    for (int off = 32; off > 0; off >>= 1) acc[h] += __shfl_xor(acc[h], off);
  }
  if (lane == 0) {
    const size_t i = row >> 9;
    const size_t j = row & (N - 1);
#pragma unroll
    for (int h = 0; h < 8; ++h)
      wbuf[((size_t)h * N + i) * N + j] = acc[h] + bb[h];
  }
}

// ---------------------------------------------------------------------------
// Kernel 4: softmax over j per (h,i) row; fp32 logits in, bf16 weights out.
// ---------------------------------------------------------------------------
__global__ __launch_bounds__(256) void k_softmax(
    const float* __restrict__ wbuf, __hip_bfloat16* __restrict__ wbh)
{
  const float* p = wbuf + (size_t)blockIdx.x * N;
  const int t = threadIdx.x, lane = t & 63, wav = t >> 6;
  float2 xv = *(const float2*)(p + t * 2);
  float mx = fmaxf(xv.x, xv.y);
#pragma unroll
  for (int off = 32; off > 0; off >>= 1) mx = fmaxf(mx, __shfl_xor(mx, off));
  __shared__ float redmax[4];
  __shared__ float redsum[4];
  if (lane == 0) redmax[wav] = mx;
  __syncthreads();
  mx = fmaxf(fmaxf(redmax[0], redmax[1]), fmaxf(redmax[2], redmax[3]));
  const float e0 = __expf(xv.x - mx), e1 = __expf(xv.y - mx);
  float sum = e0 + e1;
#pragma unroll
  for (int off = 32; off > 0; off >>= 1) sum += __shfl_xor(sum, off);
  if (lane == 0) redsum[wav] = sum;
  __syncthreads();
  sum = (redsum[0] + redsum[1]) + (redsum[2] + redsum[3]);
  const float inv = 1.f / sum;
  union { __hip_bfloat16 b[2]; int i; } pk;
  pk.b[0] = __float2bfloat16(e0 * inv);
  pk.b[1] = __float2bfloat16(e1 * inv);
  *(int*)((__hip_bfloat16*)(wbh + (size_t)blockIdx.x * N) + t * 2) = pk.i;
}

// ---------------------------------------------------------------------------
// Kernel 5 (MFMA): per h, O[i][(s,c)] = W_h[i][j] x V_h[j][(s,c)].
// Epilogue: og = g * O, bf16, in place over gb.
// ---------------------------------------------------------------------------
__global__ __launch_bounds__(256) void k_attn_mfma(
    const __hip_bfloat16* __restrict__ vc, const __hip_bfloat16* __restrict__ wbh,
    __hip_bfloat16* gb)
{
  __shared__ __hip_bfloat16 Ac[8 * 128 * 8];
  __shared__ __hip_bfloat16 Bc[8 * 128 * 8];

  const int t = threadIdx.x;
  const int wave = t >> 6, lane = t & 63;
  const int wm = wave >> 1, wn = wave & 1;
  const int lr = lane & 15, lq = lane >> 4;
  const int n0 = blockIdx.x * 128;
  const int i0 = blockIdx.y * 128;
  const int h  = blockIdx.z;

  f32x4 acc[4][4];
#pragma unroll
  for (int mi = 0; mi < 4; ++mi)
#pragma unroll
    for (int ni = 0; ni < 4; ++ni) acc[mi][ni] = (f32x4)0.f;

  const __hip_bfloat16* Abase = wbh + ((size_t)h * N + i0) * N;
  const __hip_bfloat16* Bbase = vc + (size_t)h * (N / 8) * (S * C) * 8 + (size_t)n0 * 8;

  for (int kt = 0; kt < N / 64; ++kt) {
    __syncthreads();
#pragma unroll
    for (int u = 0; u < 2; ++u) {
      const int jb = wave * 2 + u;
#pragma unroll
      for (int ih = 0; ih < 2; ++ih) {
        const __hip_bfloat16* asrc = Abase + ((size_t)(ih * 64 + lane)) * N + kt * 64 + jb * 8;
        GLOBAL_LOAD_LDS16(asrc, &Ac[(jb * 128 + ih * 64) * 8]);
        const __hip_bfloat16* bsrc = Bbase + ((size_t)(kt * 8 + jb) * (S * C) + ih * 64 + lane) * 8;
        GLOBAL_LOAD_LDS16(bsrc, &Bc[(jb * 128 + ih * 64) * 8]);
      }
    }
    __syncthreads();

#pragma unroll
    for (int kh = 0; kh < 2; ++kh) {
      const int ldb = lq + kh * 4;
      short8v a[4], b[4];
#pragma unroll
      for (int mi = 0; mi < 4; ++mi)
        a[mi] = *(const short8v*)&Ac[((ldb * 128) + wm * 64 + mi * 16 + lr) * 8];
#pragma unroll
      for (int ni = 0; ni < 4; ++ni)
        b[ni] = *(const short8v*)&Bc[((ldb * 128) + wn * 64 + ni * 16 + lr) * 8];
#pragma unroll
      for (int mi = 0; mi < 4; ++mi)
#pragma unroll
        for (int ni = 0; ni < 4; ++ni)
          acc[mi][ni] = __builtin_amdgcn_mfma_f32_16x16x32_bf16(a[mi], b[ni], acc[mi][ni], 0, 0, 0);
    }
  }

#pragma unroll
  for (int mi = 0; mi < 4; ++mi)
#pragma unroll
    for (int ni = 0; ni < 4; ++ni) {
      const int n = n0 + wn * 64 + ni * 16 + lr;
      const int sidx = n >> 5, c = n & 31;
#pragma unroll
      for (int r = 0; r < 4; ++r) {
        const int i = i0 + wm * 64 + mi * 16 + lq * 4 + r;
        const size_t idx = (((size_t)sidx * N + i) << 8) + h * C + c;
        const float gv = __bfloat162float(gb[idx]);
        gb[idx] = __float2bfloat16(gv * acc[mi][ni][r]);
      }
    }
}

// ---------------------------------------------------------------------------
// Kernel 6 (MFMA): out = og[131072x256] @ Wp[256x256], fp32 out.
// ---------------------------------------------------------------------------
__global__ __launch_bounds__(256) void k_out_mfma(
    const __hip_bfloat16* __restrict__ ogb, const __hip_bfloat16* __restrict__ Wp_t,
    float* __restrict__ out)
{
  __shared__ __hip_bfloat16 Ac[8 * 128 * 8];
  __shared__ __hip_bfloat16 Bc[8 * 128 * 8];
  const int t = threadIdx.x;
  const int wave = t >> 6, lane = t & 63;
  const int wm = wave >> 1, wn = wave & 1;
  const int lr = lane & 15, lq = lane >> 4;
  const int n0 = blockIdx.x * 128;
  const int m0 = blockIdx.y * 128;

  f32x4 acc[4][4];
#pragma unroll
  for (int mi = 0; mi < 4; ++mi)
#pragma unroll
    for (int ni = 0; ni < 4; ++ni) acc[mi][ni] = (f32x4)0.f;

  for (int kt = 0; kt < CM / 64; ++kt) {
    __syncthreads();
#pragma unroll
    for (int u = 0; u < 2; ++u) {
      const int jb = wave * 2 + u;
#pragma unroll
      for (int ih = 0; ih < 2; ++ih) {
        const __hip_bfloat16* asrc = ogb + ((size_t)(m0 + ih * 64 + lane)) * CM + kt * 64 + jb * 8;
        GLOBAL_LOAD_LDS16(asrc, &Ac[(jb * 128 + ih * 64) * 8]);
        const __hip_bfloat16* bsrc = Wp_t + ((size_t)(n0 + ih * 64 + lane)) * CM + kt * 64 + jb * 8;
        GLOBAL_LOAD_LDS16(bsrc, &Bc[(jb * 128 + ih * 64) * 8]);
      }
    }
    __syncthreads();
#pragma unroll
    for (int kh = 0; kh < 2; ++kh) {
      const int ldb = lq + kh * 4;
      short8v a[4], b[4];
#pragma unroll
      for (int mi = 0; mi < 4; ++mi)
        a[mi] = *(const short8v*)&Ac[((ldb * 128) + wm * 64 + mi * 16 + lr) * 8];
#pragma unroll
      for (int ni = 0; ni < 4; ++ni)
        b[ni] = *(const short8v*)&Bc[((ldb * 128) + wn * 64 + ni * 16 + lr) * 8];
#pragma unroll
      for (int mi = 0; mi < 4; ++mi)
#pragma unroll
        for (int ni = 0; ni < 4; ++ni)
          acc[mi][ni] = __builtin_amdgcn_mfma_f32_16x16x32_bf16(a[mi], b[ni], acc[mi][ni], 0, 0, 0);
    }
  }

#pragma unroll
  for (int mi = 0; mi < 4; ++mi) {
    const int rowb = m0 + wm * 64 + mi * 16 + lq * 4;
#pragma unroll
    for (int ni = 0; ni < 4; ++ni) {
      const int col = n0 + wn * 64 + ni * 16 + lr;
#pragma unroll
      for (int r = 0; r < 4; ++r)
        out[(size_t)(rowb + r) * CM + col] = acc[mi][ni][r];
    }
  }
}

// ---------------------------------------------------------------------------
extern "C" void kernel_launch(void* const* d_in, const int* in_sizes, int n_in,
                              void* d_out, int out_size, void* d_ws, size_t ws_size,
                              hipStream_t stream)
{
  const float* msa      = (const float*)d_in[0];
  const float* pair     = (const float*)d_in[1];
  const float* ln_msa_g = (const float*)d_in[2];
  const float* ln_msa_b = (const float*)d_in[3];
  const float* Wv       = (const float*)d_in[4];
  const float* bv       = (const float*)d_in[5];
  const float* ln_z_g   = (const float*)d_in[6];
  const float* ln_z_b   = (const float*)d_in[7];
  const float* Wb       = (const float*)d_in[8];
  const float* bb       = (const float*)d_in[9];
  const float* Wg       = (const float*)d_in[10];
  const float* bg       = (const float*)d_in[11];
  const float* Wp       = (const float*)d_in[12];
  float* out = (float*)d_out;

  // ws layout (bytes)
  char* w = (char*)d_ws;
  __hip_bfloat16* vc     = (__hip_bfloat16*)(w);                     // 67.1 MB [h][j/8][s*32+c][j%8]
  __hip_bfloat16* mbf    = (__hip_bfloat16*)(w + 67108864);          // 67.1 MB [row][k]
  __hip_bfloat16* gb     = (__hip_bfloat16*)(w + 134217728);         // 67.1 MB [row][h*32+c] (g, then og)
  float*          wbuf   = (float*)         (w + 201326592);         //  8.4 MB [h][i][j] logits
  __hip_bfloat16* wbh    = (__hip_bfloat16*)(w + 209715200);         //  4.2 MB [h][i][j] bf16
  __hip_bfloat16* Wcat_t = (__hip_bfloat16*)(w + 213909504);         //  256 KB [n][k]
  __hip_bfloat16* Wp_t   = (__hip_bfloat16*)(w + 214171648);         //  128 KB [n][k]

  k_prep<<<256, 256, 0, stream>>>(Wv, Wg, Wp, Wcat_t, Wp_t);
  k_ln<<<S * N / 4, 256, 0, stream>>>(msa, ln_msa_g, ln_msa_b, mbf);
  dim3 g1(4, S * N / 128);
  k_mm1<<<g1, 256, 0, stream>>>(mbf, Wcat_t, bv, bg, vc, gb);
  k_ln_b<<<N * N / 4, 256, 0, stream>>>(pair, ln_z_g, ln_z_b, Wb, bb, wbuf);
  k_softmax<<<N * H, 256, 0, stream>>>(wbuf, wbh);
  dim3 g4(S * C / 128, N / 128, H);
  k_attn_mfma<<<g4, 256, 0, stream>>>(vc, wbh, gb);
  dim3 g5(2, S * N / 128);
  k_out_mfma<<<g5, 256, 0, stream>>>(gb, Wp_t, out);
}

// Round 4
// 331.250 us; speedup vs baseline: 5.0523x; 1.3429x over previous
//
#include <hip/hip_runtime.h>
#include <hip/hip_bf16.h>
#include <math.h>

#define S 256
#define N 512
#define CM 256
#define CZ 128
#define H 8
#define C 32
#define HC 256

typedef __attribute__((ext_vector_type(8))) short short8v;
typedef __attribute__((ext_vector_type(4))) float f32x4;

#define GLOBAL_LOAD_LDS16(gsrc, ldst)                                          \
  __builtin_amdgcn_global_load_lds(                                            \
      (const __attribute__((address_space(1))) void*)(gsrc),                   \
      (__attribute__((address_space(3))) void*)(ldst), 16, 0, 0)

// ---------------------------------------------------------------------------
// Kernel 0: weight prep. Wcat_t[n][k] = bf16(Wv[k][n]) (n<256) / Wg[k][n-256];
// Wp_t[n][k] = bf16(Wp[k][n]).  B^T layouts for MFMA B-fragments.
// ---------------------------------------------------------------------------
__global__ __launch_bounds__(256) void k_prep(
    const float* __restrict__ Wv, const float* __restrict__ Wg, const float* __restrict__ Wp,
    __hip_bfloat16* __restrict__ Wcat_t, __hip_bfloat16* __restrict__ Wp_t)
{
  const int k = blockIdx.x;   // 256
  const int n = threadIdx.x;  // 256
  Wcat_t[(size_t)n * CM + k]        = __float2bfloat16(Wv[(size_t)k * HC + n]);
  Wcat_t[(size_t)(n + HC) * CM + k] = __float2bfloat16(Wg[(size_t)k * HC + n]);
  Wp_t[(size_t)n * CM + k]          = __float2bfloat16(Wp[(size_t)k * CM + n]);
}

// ---------------------------------------------------------------------------
// Kernel 1: row LayerNorm of msa -> bf16 [131072][256]. One wave per row.
// ---------------------------------------------------------------------------
__global__ __launch_bounds__(256) void k_ln(
    const float* __restrict__ msa, const float* __restrict__ gamma, const float* __restrict__ beta,
    __hip_bfloat16* __restrict__ mbf)
{
  const int t = threadIdx.x, wav = t >> 6, lane = t & 63;
  const size_t row = (size_t)blockIdx.x * 4 + wav;
  const int k0 = lane * 4;
  const float4 xv = *(const float4*)(msa + row * CM + k0);
  float s  = xv.x + xv.y + xv.z + xv.w;
  float s2 = xv.x * xv.x + xv.y * xv.y + xv.z * xv.z + xv.w * xv.w;
#pragma unroll
  for (int off = 32; off > 0; off >>= 1) {
    s  += __shfl_xor(s, off);
    s2 += __shfl_xor(s2, off);
  }
  const float mu = s * (1.f / CM);
  const float rstd = rsqrtf(s2 * (1.f / CM) - mu * mu + 1e-5f);
  const float4 gm = *(const float4*)(gamma + k0);
  const float4 bt = *(const float4*)(beta + k0);
  union { __hip_bfloat16 b[4]; short4 v; } pk;
  pk.b[0] = __float2bfloat16((xv.x - mu) * rstd * gm.x + bt.x);
  pk.b[1] = __float2bfloat16((xv.y - mu) * rstd * gm.y + bt.y);
  pk.b[2] = __float2bfloat16((xv.z - mu) * rstd * gm.z + bt.z);
  pk.b[3] = __float2bfloat16((xv.w - mu) * rstd * gm.w + bt.w);
  *(short4*)(mbf + row * CM + k0) = pk.v;
}

// ---------------------------------------------------------------------------
// Kernel 2 (MFMA): D = mbf[131072x256] @ Wcat[256x512] + bias.
// cols <256: v -> chunked vc [h][j/8][s*32+c][j%8] bf16 (8B packed stores)
// cols >=256: g = sigmoid   -> gb [row][col'] bf16
// ---------------------------------------------------------------------------
__global__ __launch_bounds__(256) void k_mm1(
    const __hip_bfloat16* __restrict__ mbf, const __hip_bfloat16* __restrict__ Wcat_t,
    const float* __restrict__ bv, const float* __restrict__ bg,
    __hip_bfloat16* __restrict__ vc, __hip_bfloat16* __restrict__ gb)
{
  __shared__ __hip_bfloat16 Ac[8 * 128 * 8];  // [kb][m_local][kr]
  __shared__ __hip_bfloat16 Bc[8 * 128 * 8];  // [kb][n_local][kr]
  const int t = threadIdx.x;
  const int wave = t >> 6, lane = t & 63;
  const int wm = wave >> 1, wn = wave & 1;
  const int lr = lane & 15, lq = lane >> 4;
  const int n0 = blockIdx.x * 128;
  const int m0 = blockIdx.y * 128;

  float bias[4];
#pragma unroll
  for (int ni = 0; ni < 4; ++ni) {
    const int col = n0 + wn * 64 + ni * 16 + lr;
    bias[ni] = (col < HC) ? bv[col] : bg[col - HC];
  }
  f32x4 acc[4][4];
#pragma unroll
  for (int mi = 0; mi < 4; ++mi)
#pragma unroll
    for (int ni = 0; ni < 4; ++ni) acc[mi][ni] = (f32x4)bias[ni];

  for (int kt = 0; kt < CM / 64; ++kt) {
    __syncthreads();
#pragma unroll
    for (int u = 0; u < 2; ++u) {
      const int jb = wave * 2 + u;
#pragma unroll
      for (int ih = 0; ih < 2; ++ih) {
        const __hip_bfloat16* asrc = mbf + ((size_t)(m0 + ih * 64 + lane)) * CM + kt * 64 + jb * 8;
        GLOBAL_LOAD_LDS16(asrc, &Ac[(jb * 128 + ih * 64) * 8]);
        const __hip_bfloat16* bsrc = Wcat_t + ((size_t)(n0 + ih * 64 + lane)) * CM + kt * 64 + jb * 8;
        GLOBAL_LOAD_LDS16(bsrc, &Bc[(jb * 128 + ih * 64) * 8]);
      }
    }
    __syncthreads();
#pragma unroll
    for (int kh = 0; kh < 2; ++kh) {
      const int ldb = lq + kh * 4;
      short8v a[4], b[4];
#pragma unroll
      for (int mi = 0; mi < 4; ++mi)
        a[mi] = *(const short8v*)&Ac[((ldb * 128) + wm * 64 + mi * 16 + lr) * 8];
#pragma unroll
      for (int ni = 0; ni < 4; ++ni)
        b[ni] = *(const short8v*)&Bc[((ldb * 128) + wn * 64 + ni * 16 + lr) * 8];
#pragma unroll
      for (int mi = 0; mi < 4; ++mi)
#pragma unroll
        for (int ni = 0; ni < 4; ++ni)
          acc[mi][ni] = __builtin_amdgcn_mfma_f32_16x16x32_bf16(a[mi], b[ni], acc[mi][ni], 0, 0, 0);
    }
  }

  if (n0 < HC) {  // v half -> chunked layout, 4 consecutive j per lane = 8B store
#pragma unroll
    for (int mi = 0; mi < 4; ++mi) {
      const int rowb = m0 + wm * 64 + mi * 16 + lq * 4;
      const int s = rowb >> 9;
      const int j = rowb & (N - 1);
      const int jb = j >> 3, jlo = (lq & 1) * 4;
#pragma unroll
      for (int ni = 0; ni < 4; ++ni) {
        const int col = n0 + wn * 64 + ni * 16 + lr;
        const int h = col >> 5, c = col & 31;
        union { __hip_bfloat16 b[4]; short4 v; } pk;
#pragma unroll
        for (int r = 0; r < 4; ++r) pk.b[r] = __float2bfloat16(acc[mi][ni][r]);
        *(short4*)(vc + ((size_t)(h * (N / 8) + jb) * (S * C) + s * C + c) * 8 + jlo) = pk.v;
      }
    }
  } else {  // g half
#pragma unroll
    for (int mi = 0; mi < 4; ++mi) {
      const int rowb = m0 + wm * 64 + mi * 16 + lq * 4;
#pragma unroll
      for (int ni = 0; ni < 4; ++ni) {
        const int colp = (n0 - HC) + wn * 64 + ni * 16 + lr;
#pragma unroll
        for (int r = 0; r < 4; ++r)
          gb[(size_t)(rowb + r) * HC + colp] =
              __float2bfloat16(1.f / (1.f + __expf(-acc[mi][ni][r])));
      }
    }
  }
}

// ---------------------------------------------------------------------------
// Kernel 3: LayerNorm(pair) @ Wb -> logits [h][i][j] fp32.
// 16 lanes per row (8 elems/lane): 40 shfl per 4 rows vs 60 per row before.
// Wb kept in per-thread registers (k-range fixed by lane&15), amortized over
// 128 rows per block. bb dropped: softmax is shift-invariant.
// ---------------------------------------------------------------------------
__global__ __launch_bounds__(256) void k_ln_b(
    const float* __restrict__ pair, const float* __restrict__ gamma, const float* __restrict__ beta,
    const float* __restrict__ Wb, float* __restrict__ wbuf)
{
  const int t = threadIdx.x, wav = t >> 6, lane = t & 63;
  const int q = lane & 15, sub = lane >> 4;  // 4 rows per wave
  const int k0 = q * 8;

  // per-thread Wb block: rows k0..k0+7, all 8 heads (64 VGPRs)
  float wreg[8][8];
#pragma unroll
  for (int kk = 0; kk < 8; ++kk) {
    *(float4*)&wreg[kk][0] = *(const float4*)&Wb[(k0 + kk) * H];
    *(float4*)&wreg[kk][4] = *(const float4*)&Wb[(k0 + kk) * H + 4];
  }
  const float4 gm0 = *(const float4*)(gamma + k0);
  const float4 gm1 = *(const float4*)(gamma + k0 + 4);
  const float4 bt0 = *(const float4*)(beta + k0);
  const float4 bt1 = *(const float4*)(beta + k0 + 4);

  // 128 rows per block: 8 iterations x (4 waves x 4 rows)
#pragma unroll 2
  for (int it = 0; it < 8; ++it) {
    const size_t row = (size_t)blockIdx.x * 128 + it * 16 + wav * 4 + sub;
    const float* x = pair + row * CZ + k0;
    const float4 x0 = *(const float4*)(x);
    const float4 x1 = *(const float4*)(x + 4);

    float s  = x0.x + x0.y + x0.z + x0.w + x1.x + x1.y + x1.z + x1.w;
    float s2 = x0.x * x0.x + x0.y * x0.y + x0.z * x0.z + x0.w * x0.w
             + x1.x * x1.x + x1.y * x1.y + x1.z * x1.z + x1.w * x1.w;
#pragma unroll
    for (int off = 8; off > 0; off >>= 1) {
      s  += __shfl_xor(s, off);
      s2 += __shfl_xor(s2, off);
    }
    const float mu = s * (1.f / CZ);
    const float rstd = rsqrtf(s2 * (1.f / CZ) - mu * mu + 1e-5f);

    float xn[8];
    xn[0] = (x0.x - mu) * rstd * gm0.x + bt0.x;
    xn[1] = (x0.y - mu) * rstd * gm0.y + bt0.y;
    xn[2] = (x0.z - mu) * rstd * gm0.z + bt0.z;
    xn[3] = (x0.w - mu) * rstd * gm0.w + bt0.w;
    xn[4] = (x1.x - mu) * rstd * gm1.x + bt1.x;
    xn[5] = (x1.y - mu) * rstd * gm1.y + bt1.y;
    xn[6] = (x1.z - mu) * rstd * gm1.z + bt1.z;
    xn[7] = (x1.w - mu) * rstd * gm1.w + bt1.w;

    float acc[8];
#pragma unroll
    for (int h = 0; h < 8; ++h) acc[h] = 0.f;
#pragma unroll
    for (int kk = 0; kk < 8; ++kk)
#pragma unroll
      for (int h = 0; h < 8; ++h) acc[h] += xn[kk] * wreg[kk][h];

#pragma unroll
    for (int h = 0; h < 8; ++h) {
#pragma unroll
      for (int off = 8; off > 0; off >>= 1) acc[h] += __shfl_xor(acc[h], off);
    }
    if (q == 0) {
      const size_t i = row >> 9;
      const size_t j = row & (N - 1);
#pragma unroll
      for (int h = 0; h < 8; ++h)
        wbuf[((size_t)h * N + i) * N + j] = acc[h];
    }
  }
}

// ---------------------------------------------------------------------------
// Kernel 4: softmax over j per (h,i) row; fp32 logits in, bf16 weights out.
// ---------------------------------------------------------------------------
__global__ __launch_bounds__(256) void k_softmax(
    const float* __restrict__ wbuf, __hip_bfloat16* __restrict__ wbh)
{
  const float* p = wbuf + (size_t)blockIdx.x * N;
  const int t = threadIdx.x, lane = t & 63, wav = t >> 6;
  float2 xv = *(const float2*)(p + t * 2);
  float mx = fmaxf(xv.x, xv.y);
#pragma unroll
  for (int off = 32; off > 0; off >>= 1) mx = fmaxf(mx, __shfl_xor(mx, off));
  __shared__ float redmax[4];
  __shared__ float redsum[4];
  if (lane == 0) redmax[wav] = mx;
  __syncthreads();
  mx = fmaxf(fmaxf(redmax[0], redmax[1]), fmaxf(redmax[2], redmax[3]));
  const float e0 = __expf(xv.x - mx), e1 = __expf(xv.y - mx);
  float sum = e0 + e1;
#pragma unroll
  for (int off = 32; off > 0; off >>= 1) sum += __shfl_xor(sum, off);
  if (lane == 0) redsum[wav] = sum;
  __syncthreads();
  sum = (redsum[0] + redsum[1]) + (redsum[2] + redsum[3]);
  const float inv = 1.f / sum;
  union { __hip_bfloat16 b[2]; int i; } pk;
  pk.b[0] = __float2bfloat16(e0 * inv);
  pk.b[1] = __float2bfloat16(e1 * inv);
  *(int*)((__hip_bfloat16*)(wbh + (size_t)blockIdx.x * N) + t * 2) = pk.i;
}

// ---------------------------------------------------------------------------
// Kernel 5 (MFMA): per h, O[i][(s,c)] = W_h[i][j] x V_h[j][(s,c)].
// Epilogue: og = g * O, bf16, in place over gb.
// ---------------------------------------------------------------------------
__global__ __launch_bounds__(256) void k_attn_mfma(
    const __hip_bfloat16* __restrict__ vc, const __hip_bfloat16* __restrict__ wbh,
    __hip_bfloat16* gb)
{
  __shared__ __hip_bfloat16 Ac[8 * 128 * 8];
  __shared__ __hip_bfloat16 Bc[8 * 128 * 8];

  const int t = threadIdx.x;
  const int wave = t >> 6, lane = t & 63;
  const int wm = wave >> 1, wn = wave & 1;
  const int lr = lane & 15, lq = lane >> 4;
  const int n0 = blockIdx.x * 128;
  const int i0 = blockIdx.y * 128;
  const int h  = blockIdx.z;

  f32x4 acc[4][4];
#pragma unroll
  for (int mi = 0; mi < 4; ++mi)
#pragma unroll
    for (int ni = 0; ni < 4; ++ni) acc[mi][ni] = (f32x4)0.f;

  const __hip_bfloat16* Abase = wbh + ((size_t)h * N + i0) * N;
  const __hip_bfloat16* Bbase = vc + (size_t)h * (N / 8) * (S * C) * 8 + (size_t)n0 * 8;

  for (int kt = 0; kt < N / 64; ++kt) {
    __syncthreads();
#pragma unroll
    for (int u = 0; u < 2; ++u) {
      const int jb = wave * 2 + u;
#pragma unroll
      for (int ih = 0; ih < 2; ++ih) {
        const __hip_bfloat16* asrc = Abase + ((size_t)(ih * 64 + lane)) * N + kt * 64 + jb * 8;
        GLOBAL_LOAD_LDS16(asrc, &Ac[(jb * 128 + ih * 64) * 8]);
        const __hip_bfloat16* bsrc = Bbase + ((size_t)(kt * 8 + jb) * (S * C) + ih * 64 + lane) * 8;
        GLOBAL_LOAD_LDS16(bsrc, &Bc[(jb * 128 + ih * 64) * 8]);
      }
    }
    __syncthreads();

#pragma unroll
    for (int kh = 0; kh < 2; ++kh) {
      const int ldb = lq + kh * 4;
      short8v a[4], b[4];
#pragma unroll
      for (int mi = 0; mi < 4; ++mi)
        a[mi] = *(const short8v*)&Ac[((ldb * 128) + wm * 64 + mi * 16 + lr) * 8];
#pragma unroll
      for (int ni = 0; ni < 4; ++ni)
        b[ni] = *(const short8v*)&Bc[((ldb * 128) + wn * 64 + ni * 16 + lr) * 8];
#pragma unroll
      for (int mi = 0; mi < 4; ++mi)
#pragma unroll
        for (int ni = 0; ni < 4; ++ni)
          acc[mi][ni] = __builtin_amdgcn_mfma_f32_16x16x32_bf16(a[mi], b[ni], acc[mi][ni], 0, 0, 0);
    }
  }

#pragma unroll
  for (int mi = 0; mi < 4; ++mi)
#pragma unroll
    for (int ni = 0; ni < 4; ++ni) {
      const int n = n0 + wn * 64 + ni * 16 + lr;
      const int sidx = n >> 5, c = n & 31;
#pragma unroll
      for (int r = 0; r < 4; ++r) {
        const int i = i0 + wm * 64 + mi * 16 + lq * 4 + r;
        const size_t idx = (((size_t)sidx * N + i) << 8) + h * C + c;
        const float gv = __bfloat162float(gb[idx]);
        gb[idx] = __float2bfloat16(gv * acc[mi][ni][r]);
      }
    }
}

// ---------------------------------------------------------------------------
// Kernel 6 (MFMA): out = og[131072x256] @ Wp[256x256], fp32 out.
// ---------------------------------------------------------------------------
__global__ __launch_bounds__(256) void k_out_mfma(
    const __hip_bfloat16* __restrict__ ogb, const __hip_bfloat16* __restrict__ Wp_t,
    float* __restrict__ out)
{
  __shared__ __hip_bfloat16 Ac[8 * 128 * 8];
  __shared__ __hip_bfloat16 Bc[8 * 128 * 8];
  const int t = threadIdx.x;
  const int wave = t >> 6, lane = t & 63;
  const int wm = wave >> 1, wn = wave & 1;
  const int lr = lane & 15, lq = lane >> 4;
  const int n0 = blockIdx.x * 128;
  const int m0 = blockIdx.y * 128;

  f32x4 acc[4][4];
#pragma unroll
  for (int mi = 0; mi < 4; ++mi)
#pragma unroll
    for (int ni = 0; ni < 4; ++ni) acc[mi][ni] = (f32x4)0.f;

  for (int kt = 0; kt < CM / 64; ++kt) {
    __syncthreads();
#pragma unroll
    for (int u = 0; u < 2; ++u) {
      const int jb = wave * 2 + u;
#pragma unroll
      for (int ih = 0; ih < 2; ++ih) {
        const __hip_bfloat16* asrc = ogb + ((size_t)(m0 + ih * 64 + lane)) * CM + kt * 64 + jb * 8;
        GLOBAL_LOAD_LDS16(asrc, &Ac[(jb * 128 + ih * 64) * 8]);
        const __hip_bfloat16* bsrc = Wp_t + ((size_t)(n0 + ih * 64 + lane)) * CM + kt * 64 + jb * 8;
        GLOBAL_LOAD_LDS16(bsrc, &Bc[(jb * 128 + ih * 64) * 8]);
      }
    }
    __syncthreads();
#pragma unroll
    for (int kh = 0; kh < 2; ++kh) {
      const int ldb = lq + kh * 4;
      short8v a[4], b[4];
#pragma unroll
      for (int mi = 0; mi < 4; ++mi)
        a[mi] = *(const short8v*)&Ac[((ldb * 128) + wm * 64 + mi * 16 + lr) * 8];
#pragma unroll
      for (int ni = 0; ni < 4; ++ni)
        b[ni] = *(const short8v*)&Bc[((ldb * 128) + wn * 64 + ni * 16 + lr) * 8];
#pragma unroll
      for (int mi = 0; mi < 4; ++mi)
#pragma unroll
        for (int ni = 0; ni < 4; ++ni)
          acc[mi][ni] = __builtin_amdgcn_mfma_f32_16x16x32_bf16(a[mi], b[ni], acc[mi][ni], 0, 0, 0);
    }
  }

#pragma unroll
  for (int mi = 0; mi < 4; ++mi) {
    const int rowb = m0 + wm * 64 + mi * 16 + lq * 4;
#pragma unroll
    for (int ni = 0; ni < 4; ++ni) {
      const int col = n0 + wn * 64 + ni * 16 + lr;
#pragma unroll
      for (int r = 0; r < 4; ++r)
        out[(size_t)(rowb + r) * CM + col] = acc[mi][ni][r];
    }
  }
}

// ---------------------------------------------------------------------------
extern "C" void kernel_launch(void* const* d_in, const int* in_sizes, int n_in,
                              void* d_out, int out_size, void* d_ws, size_t ws_size,
                              hipStream_t stream)
{
  const float* msa      = (const float*)d_in[0];
  const float* pair     = (const float*)d_in[1];
  const float* ln_msa_g = (const float*)d_in[2];
  const float* ln_msa_b = (const float*)d_in[3];
  const float* Wv       = (const float*)d_in[4];
  const float* bv       = (const float*)d_in[5];
  const float* ln_z_g   = (const float*)d_in[6];
  const float* ln_z_b   = (const float*)d_in[7];
  const float* Wb       = (const float*)d_in[8];
  const float* bb       = (const float*)d_in[9];
  const float* Wg       = (const float*)d_in[10];
  const float* bg       = (const float*)d_in[11];
  const float* Wp       = (const float*)d_in[12];
  float* out = (float*)d_out;
  (void)bb;  // softmax is shift-invariant; bb cancels

  // ws layout (bytes)
  char* w = (char*)d_ws;
  __hip_bfloat16* vc     = (__hip_bfloat16*)(w);                     // 67.1 MB [h][j/8][s*32+c][j%8]
  __hip_bfloat16* mbf    = (__hip_bfloat16*)(w + 67108864);          // 67.1 MB [row][k]
  __hip_bfloat16* gb     = (__hip_bfloat16*)(w + 134217728);         // 67.1 MB [row][h*32+c] (g, then og)
  float*          wbuf   = (float*)         (w + 201326592);         //  8.4 MB [h][i][j] logits
  __hip_bfloat16* wbh    = (__hip_bfloat16*)(w + 209715200);         //  4.2 MB [h][i][j] bf16
  __hip_bfloat16* Wcat_t = (__hip_bfloat16*)(w + 213909504);         //  256 KB [n][k]
  __hip_bfloat16* Wp_t   = (__hip_bfloat16*)(w + 214171648);         //  128 KB [n][k]

  k_prep<<<256, 256, 0, stream>>>(Wv, Wg, Wp, Wcat_t, Wp_t);
  k_ln<<<S * N / 4, 256, 0, stream>>>(msa, ln_msa_g, ln_msa_b, mbf);
  dim3 g1(4, S * N / 128);
  k_mm1<<<g1, 256, 0, stream>>>(mbf, Wcat_t, bv, bg, vc, gb);
  k_ln_b<<<N * N / 128, 256, 0, stream>>>(pair, ln_z_g, ln_z_b, Wb, wbuf);
  k_softmax<<<N * H, 256, 0, stream>>>(wbuf, wbh);
  dim3 g4(S * C / 128, N / 128, H);
  k_attn_mfma<<<g4, 256, 0, stream>>>(vc, wbh, gb);
  dim3 g5(2, S * N / 128);
  k_out_mfma<<<g5, 256, 0, stream>>>(gb, Wp_t, out);
}